// Round 1
// baseline (2673.108 us; speedup 1.0000x reference)
//
#include <hip/hip_runtime.h>
#include <math.h>

#define IMG   56
#define WINSZ 7
#define SHIFTSZ 3
#define CDIM  256
#define NH    8
#define DH    32
#define SEQ   49      // WINSZ*WINSZ
#define NYW   8       // IMG/WINSZ
#define NWIN  64      // NYW*NYW
#define NMLP  1024
#define BATCH 32
#define NTOK  (BATCH*IMG*IMG)   // 100352
#define BNW   (BATCH*NWIN)      // 2048
#define QSCALE 0.17677669529663687f   // 32^-0.5
#define EPSLN 1e-5f

// ---------------------------------------------------------------------------
// LayerNorm; WINDOWED=1 also applies roll(-3,-3) + window partition:
// out token order = [b, wy, wx, i, j], source pixel = ((wy*7+i+3)%56, (wx*7+j+3)%56)
// ---------------------------------------------------------------------------
template<int WINDOWED>
__global__ __launch_bounds__(256) void ln_kernel(const float* __restrict__ x,
                                                 const float* __restrict__ gamma,
                                                 const float* __restrict__ beta,
                                                 float* __restrict__ out) {
    int wave = threadIdx.x >> 6;
    int lane = threadIdx.x & 63;
    int tok  = blockIdx.x * 4 + wave;
    int src  = tok;
    if (WINDOWED) {
        int b  = tok / (NWIN * SEQ);
        int r  = tok - b * (NWIN * SEQ);
        int wl = r / SEQ, s = r - wl * SEQ;
        int wy = wl >> 3, wx = wl & 7;
        int i  = s / WINSZ, j = s - i * WINSZ;
        int hp = wy * WINSZ + i + SHIFTSZ; if (hp >= IMG) hp -= IMG;
        int wp = wx * WINSZ + j + SHIFTSZ; if (wp >= IMG) wp -= IMG;
        src = b * (IMG * IMG) + hp * IMG + wp;
    }
    float4 v = *(const float4*)(x + (size_t)src * CDIM + lane * 4);
    float sum = v.x + v.y + v.z + v.w;
    float ss  = v.x*v.x + v.y*v.y + v.z*v.z + v.w*v.w;
#pragma unroll
    for (int off = 32; off; off >>= 1) {
        sum += __shfl_xor(sum, off);
        ss  += __shfl_xor(ss,  off);
    }
    float mu   = sum * (1.0f / CDIM);
    float var  = ss * (1.0f / CDIM) - mu * mu;
    float rstd = rsqrtf(var + EPSLN);
    float4 g  = *(const float4*)(gamma + lane * 4);
    float4 be = *(const float4*)(beta  + lane * 4);
    float4 o;
    o.x = (v.x - mu) * rstd * g.x + be.x;
    o.y = (v.y - mu) * rstd * g.y + be.y;
    o.z = (v.z - mu) * rstd * g.z + be.z;
    o.w = (v.w - mu) * rstd * g.w + be.w;
    *(float4*)(out + (size_t)tok * CDIM + lane * 4) = o;
}

// ---------------------------------------------------------------------------
// fp32 tiled GEMM core: 64x64 tile, BK=32, 256 threads, 4x4 per thread.
// A row-major [M,K] (lda), B row-major [K,N] (ldb).
// ---------------------------------------------------------------------------
#define BM 64
#define BN 64
#define BKK 32
#define AS_LD 36   // padded leading dim (16B-aligned rows, few bank conflicts)

__device__ __forceinline__ void gemm_tile(const float* __restrict__ A,
                                          const float* __restrict__ Bm,
                                          int lda, int ldb, int K,
                                          int rowBase, int colBase,
                                          float* As, float* Bs, float acc[4][4]) {
    int tid = threadIdx.x;
    int tx = tid & 15, ty = tid >> 4;
#pragma unroll
    for (int i = 0; i < 4; i++)
#pragma unroll
        for (int j = 0; j < 4; j++) acc[i][j] = 0.0f;
    int a_r = tid >> 3, a_c = (tid & 7) * 4;   // 64x32 A tile: rows a_r, a_r+32
    int b_r = tid >> 4, b_c = (tid & 15) * 4;  // 32x64 B tile: rows b_r, b_r+16
    for (int k0 = 0; k0 < K; k0 += BKK) {
        float4 a0 = *(const float4*)(A + (size_t)(rowBase + a_r)      * lda + k0 + a_c);
        float4 a1 = *(const float4*)(A + (size_t)(rowBase + a_r + 32) * lda + k0 + a_c);
        float4 b0 = *(const float4*)(Bm + (size_t)(k0 + b_r)      * ldb + colBase + b_c);
        float4 b1 = *(const float4*)(Bm + (size_t)(k0 + b_r + 16) * ldb + colBase + b_c);
        __syncthreads();
        *(float4*)(As + (a_r)      * AS_LD + a_c) = a0;
        *(float4*)(As + (a_r + 32) * AS_LD + a_c) = a1;
        *(float4*)(Bs + (b_r)      * BN + b_c) = b0;
        *(float4*)(Bs + (b_r + 16) * BN + b_c) = b1;
        __syncthreads();
#pragma unroll
        for (int kk4 = 0; kk4 < BKK / 4; kk4++) {
            float4 af[4], bf[4];
#pragma unroll
            for (int i = 0; i < 4; i++)
                af[i] = *(const float4*)(As + (ty * 4 + i) * AS_LD + kk4 * 4);
#pragma unroll
            for (int r = 0; r < 4; r++)
                bf[r] = *(const float4*)(Bs + (kk4 * 4 + r) * BN + tx * 4);
#pragma unroll
            for (int i = 0; i < 4; i++) {
                const float* ap = (const float*)&af[i];
#pragma unroll
                for (int r = 0; r < 4; r++) {
                    const float* bp = (const float*)&bf[r];
                    float a = ap[r];
                    acc[i][0] += a * bp[0];
                    acc[i][1] += a * bp[1];
                    acc[i][2] += a * bp[2];
                    acc[i][3] += a * bp[3];
                }
            }
        }
    }
}

// ---- QKV GEMM: [NTOK,256]@[256,768]+b -> q,k,v [BnW,H,S,DH], q pre-scaled ----
__global__ __launch_bounds__(256) void gemm_qkv(const float* __restrict__ xw,
                                                const float* __restrict__ W,
                                                const float* __restrict__ bias,
                                                float* __restrict__ q,
                                                float* __restrict__ k,
                                                float* __restrict__ v) {
    __shared__ float As[BM * AS_LD];
    __shared__ float Bs[BKK * BN];
    float acc[4][4];
    int rowBase = blockIdx.x * BM, colBase = blockIdx.y * BN;
    gemm_tile(xw, W, CDIM, 3 * CDIM, CDIM, rowBase, colBase, As, Bs, acc);
    int tx = threadIdx.x & 15, ty = threadIdx.x >> 4;
    int n0 = colBase + tx * 4;
    int three = n0 >> 8, hh = (n0 >> 5) & 7, d0 = n0 & 31;
    float* dst = (three == 0) ? q : ((three == 1) ? k : v);
    float sc = (three == 0) ? QSCALE : 1.0f;
    float4 bv = *(const float4*)(bias + n0);
#pragma unroll
    for (int i = 0; i < 4; i++) {
        int m = rowBase + ty * 4 + i;
        int w = m / SEQ, s = m - w * SEQ;
        size_t idx = (((size_t)w * NH + hh) * SEQ + s) * DH + d0;
        float4 o;
        o.x = (acc[i][0] + bv.x) * sc;
        o.y = (acc[i][1] + bv.y) * sc;
        o.z = (acc[i][2] + bv.z) * sc;
        o.w = (acc[i][3] + bv.w) * sc;
        *(float4*)(dst + idx) = o;
    }
}

// ---- proj GEMM + window-reverse + roll(+3,+3) + residual -> y1 ----
__global__ __launch_bounds__(256) void gemm_proj(const float* __restrict__ Ain,
                                                 const float* __restrict__ W,
                                                 const float* __restrict__ bias,
                                                 const float* __restrict__ xres,
                                                 float* __restrict__ y1) {
    __shared__ float As[BM * AS_LD];
    __shared__ float Bs[BKK * BN];
    float acc[4][4];
    int rowBase = blockIdx.x * BM, colBase = blockIdx.y * BN;
    gemm_tile(Ain, W, CDIM, CDIM, CDIM, rowBase, colBase, As, Bs, acc);
    int tx = threadIdx.x & 15, ty = threadIdx.x >> 4;
    int n0 = colBase + tx * 4;
    float4 bv = *(const float4*)(bias + n0);
#pragma unroll
    for (int i = 0; i < 4; i++) {
        int m = rowBase + ty * 4 + i;
        int w = m / SEQ, s = m - w * SEQ;
        int b = w >> 6, wl = w & 63;
        int wy = wl >> 3, wx = wl & 7;
        int ii = s / WINSZ, jj = s - ii * WINSZ;
        int hp = wy * WINSZ + ii + SHIFTSZ; if (hp >= IMG) hp -= IMG;
        int wp = wx * WINSZ + jj + SHIFTSZ; if (wp >= IMG) wp -= IMG;
        size_t tok = (size_t)b * (IMG * IMG) + hp * IMG + wp;
        float4 xr = *(const float4*)(xres + tok * CDIM + n0);
        float4 o;
        o.x = xr.x + acc[i][0] + bv.x;
        o.y = xr.y + acc[i][1] + bv.y;
        o.z = xr.z + acc[i][2] + bv.z;
        o.w = xr.w + acc[i][3] + bv.w;
        *(float4*)(y1 + tok * CDIM + n0) = o;
    }
}

// ---- MLP1: [M,256]@[256,1024]+b -> exact GELU -> hbuf ----
__global__ __launch_bounds__(256) void gemm_mlp1(const float* __restrict__ A,
                                                 const float* __restrict__ W,
                                                 const float* __restrict__ bias,
                                                 float* __restrict__ hbuf) {
    __shared__ float As[BM * AS_LD];
    __shared__ float Bs[BKK * BN];
    float acc[4][4];
    int rowBase = blockIdx.x * BM, colBase = blockIdx.y * BN;
    gemm_tile(A, W, CDIM, NMLP, CDIM, rowBase, colBase, As, Bs, acc);
    int tx = threadIdx.x & 15, ty = threadIdx.x >> 4;
    int n0 = colBase + tx * 4;
    float4 bv = *(const float4*)(bias + n0);
#pragma unroll
    for (int i = 0; i < 4; i++) {
        int m = rowBase + ty * 4 + i;
        float4 o;
        float t0 = acc[i][0] + bv.x;
        float t1 = acc[i][1] + bv.y;
        float t2 = acc[i][2] + bv.z;
        float t3 = acc[i][3] + bv.w;
        o.x = 0.5f * t0 * (1.0f + erff(t0 * 0.70710678118654752f));
        o.y = 0.5f * t1 * (1.0f + erff(t1 * 0.70710678118654752f));
        o.z = 0.5f * t2 * (1.0f + erff(t2 * 0.70710678118654752f));
        o.w = 0.5f * t3 * (1.0f + erff(t3 * 0.70710678118654752f));
        *(float4*)(hbuf + (size_t)m * NMLP + n0) = o;
    }
}

// ---- MLP2: [M,1024]@[1024,256]+b + residual -> out ----
__global__ __launch_bounds__(256) void gemm_mlp2(const float* __restrict__ A,
                                                 const float* __restrict__ W,
                                                 const float* __restrict__ bias,
                                                 const float* __restrict__ y1,
                                                 float* __restrict__ outp) {
    __shared__ float As[BM * AS_LD];
    __shared__ float Bs[BKK * BN];
    float acc[4][4];
    int rowBase = blockIdx.x * BM, colBase = blockIdx.y * BN;
    gemm_tile(A, W, NMLP, CDIM, NMLP, rowBase, colBase, As, Bs, acc);
    int tx = threadIdx.x & 15, ty = threadIdx.x >> 4;
    int n0 = colBase + tx * 4;
    float4 bv = *(const float4*)(bias + n0);
#pragma unroll
    for (int i = 0; i < 4; i++) {
        int m = rowBase + ty * 4 + i;
        float4 r = *(const float4*)(y1 + (size_t)m * CDIM + n0);
        float4 o;
        o.x = r.x + acc[i][0] + bv.x;
        o.y = r.y + acc[i][1] + bv.y;
        o.z = r.z + acc[i][2] + bv.z;
        o.w = r.w + acc[i][3] + bv.w;
        *(float4*)(outp + (size_t)m * CDIM + n0) = o;
    }
}

// ---------------------------------------------------------------------------
// Attention: one block per (window, head). S=49, DH=32.
// Scores + rel-bias (on the fly) + shift mask (analytic region labels),
// softmax, PV. Output layout [BnW, S, C] with C = h*32+d.
// ---------------------------------------------------------------------------
__device__ __forceinline__ int region_label(int hp, int wp) {
    // column range [49,53) is never written in the reference mask -> label 0
    if (wp >= IMG - WINSZ && wp < IMG - SHIFTSZ) return 0;
    int lh = (hp < IMG - WINSZ) ? 0 : ((hp < IMG - SHIFTSZ) ? 1 : 2);
    int lw = (wp < IMG - WINSZ) ? 0 : 2;
    return lh * 3 + lw;
}

__global__ __launch_bounds__(256) void attn_kernel(const float* __restrict__ q,
                                                   const float* __restrict__ k,
                                                   const float* __restrict__ v,
                                                   const float* __restrict__ rel_tab,
                                                   float* __restrict__ outp) {
    int bx = blockIdx.x;
    int w = bx >> 3, h = bx & 7;
    __shared__ float lq[SEQ * 36];
    __shared__ float lk[SEQ * 36];
    __shared__ float lv[SEQ * 32];
    __shared__ float sc[SEQ * 50];
    __shared__ float rowmax[SEQ], rowinv[SEQ];
    int tid = threadIdx.x;
    const float* qg = q + (size_t)(w * NH + h) * SEQ * DH;
    const float* kg = k + (size_t)(w * NH + h) * SEQ * DH;
    const float* vg = v + (size_t)(w * NH + h) * SEQ * DH;
    for (int idx = tid; idx < SEQ * 8; idx += 256) {   // 392 float4s each
        int s = idx >> 3, r = (idx & 7) * 4;
        *(float4*)(lq + s * 36 + r) = *(const float4*)(qg + idx * 4);
        *(float4*)(lk + s * 36 + r) = *(const float4*)(kg + idx * 4);
        *(float4*)(lv + s * 32 + r) = *(const float4*)(vg + idx * 4);
    }
    int wl = w & 63;
    int wy = wl >> 3, wx = wl & 7;
    __syncthreads();
    for (int e = tid; e < SEQ * SEQ; e += 256) {
        int s = e / SEQ, t = e - s * SEQ;
        const float4* qv = (const float4*)(lq + s * 36);
        const float4* kv = (const float4*)(lk + t * 36);
        float a = 0.0f;
#pragma unroll
        for (int r = 0; r < 8; r++) {
            float4 qa = qv[r], ka = kv[r];
            a += qa.x * ka.x + qa.y * ka.y + qa.z * ka.z + qa.w * ka.w;
        }
        int is = s / WINSZ, js = s - is * WINSZ;
        int it = t / WINSZ, jt = t - it * WINSZ;
        a += rel_tab[((is - it + 6) * 13 + (js - jt + 6)) * NH + h];
        int ls = region_label(wy * WINSZ + is, wx * WINSZ + js);
        int lt = region_label(wy * WINSZ + it, wx * WINSZ + jt);
        if (ls != lt) a -= 100.0f;
        sc[s * 50 + t] = a;
    }
    __syncthreads();
    if (tid < SEQ) {
        float m = -1e30f;
        for (int t = 0; t < SEQ; t++) m = fmaxf(m, sc[tid * 50 + t]);
        rowmax[tid] = m;
    }
    __syncthreads();
    for (int e = tid; e < SEQ * SEQ; e += 256) {
        int s = e / SEQ, t = e - s * SEQ;
        sc[s * 50 + t] = expf(sc[s * 50 + t] - rowmax[s]);
    }
    __syncthreads();
    if (tid < SEQ) {
        float sm = 0.0f;
        for (int t = 0; t < SEQ; t++) sm += sc[tid * 50 + t];
        rowinv[tid] = 1.0f / sm;
    }
    __syncthreads();
    for (int e = tid; e < SEQ * DH; e += 256) {
        int s = e >> 5, d = e & 31;
        float a = 0.0f;
        for (int t = 0; t < SEQ; t++) a += sc[s * 50 + t] * lv[t * 32 + d];
        a *= rowinv[s];
        outp[((size_t)w * SEQ + s) * CDIM + h * DH + d] = a;
    }
}

// ---------------------------------------------------------------------------
extern "C" void kernel_launch(void* const* d_in, const int* in_sizes, int n_in,
                              void* d_out, int out_size, void* d_ws, size_t ws_size,
                              hipStream_t stream) {
    const float* x      = (const float*)d_in[0];
    const float* gamma  = (const float*)d_in[1];
    const float* beta   = (const float*)d_in[2];
    const float* qkv_w  = (const float*)d_in[3];
    const float* qkv_b  = (const float*)d_in[4];
    const float* proj_w = (const float*)d_in[5];
    const float* proj_b = (const float*)d_in[6];
    const float* rel_t  = (const float*)d_in[7];
    const float* mlp_w1 = (const float*)d_in[8];
    const float* mlp_b1 = (const float*)d_in[9];
    const float* mlp_w2 = (const float*)d_in[10];
    const float* mlp_b2 = (const float*)d_in[11];
    float* outp = (float*)d_out;

    const size_t SZ = (size_t)NTOK * CDIM;   // 25,690,112 floats
    float* buf0 = (float*)d_ws;      // xw, then attn_out
    float* buf1 = buf0 + SZ;         // q, then y1
    float* buf2 = buf1 + SZ;         // k, then xn2
    float* buf3 = buf2 + SZ;         // v, then MLP hidden chunk

    // 1. LN + shift + window partition
    ln_kernel<1><<<NTOK / 4, 256, 0, stream>>>(x, gamma, beta, buf0);
    // 2. QKV GEMM
    dim3 g_qkv(NTOK / BM, (3 * CDIM) / BN);
    gemm_qkv<<<g_qkv, 256, 0, stream>>>(buf0, qkv_w, qkv_b, buf1, buf2, buf3);
    // 3. Attention -> buf0
    attn_kernel<<<BNW * NH, 256, 0, stream>>>(buf1, buf2, buf3, rel_t, buf0);
    // 4. Proj + reverse + residual -> y1 (buf1)
    dim3 g_proj(NTOK / BM, CDIM / BN);
    gemm_proj<<<g_proj, 256, 0, stream>>>(buf0, proj_w, proj_b, x, buf1);
    // 5. LN2 -> buf2
    ln_kernel<0><<<NTOK / 4, 256, 0, stream>>>(buf1, gamma, beta, buf2);
    // 6/7. MLP in 4 token chunks (hidden reuses buf3)
    const int CH = NTOK / 4;   // 25088
    for (int c = 0; c < 4; c++) {
        dim3 g1(CH / BM, NMLP / BN);
        gemm_mlp1<<<g1, 256, 0, stream>>>(buf2 + (size_t)c * CH * CDIM, mlp_w1, mlp_b1, buf3);
        dim3 g2(CH / BM, CDIM / BN);
        gemm_mlp2<<<g2, 256, 0, stream>>>(buf3, mlp_w2, mlp_b2,
                                          buf1 + (size_t)c * CH * CDIM,
                                          outp + (size_t)c * CH * CDIM);
    }
}

// Round 2
// 931.919 us; speedup vs baseline: 2.8684x; 2.8684x over previous
//
#include <hip/hip_runtime.h>
#include <math.h>

#define IMG   56
#define WINSZ 7
#define SHIFTSZ 3
#define CDIM  256
#define NH    8
#define DH    32
#define SEQ   49
#define NYW   8
#define NWIN  64
#define NMLP  1024
#define BATCH 32
#define NTOK  (BATCH*IMG*IMG)       // 100352
#define BNW   (BATCH*NWIN)          // 2048
#define SZT   ((size_t)NTOK*CDIM)   // 25,690,112
#define QSCALE 0.17677669529663687f
#define EPSLN 1e-5f

typedef __attribute__((ext_vector_type(8))) short short8;
typedef __attribute__((ext_vector_type(4))) float f32x4;

__device__ __forceinline__ float bf2f(unsigned short u) {
    union { unsigned i; float f; } c; c.i = ((unsigned)u) << 16; return c.f;
}
__device__ __forceinline__ unsigned short f2bf(float f) {
    union { float f; unsigned i; } c; c.f = f;
    unsigned r = c.i + 0x7fffu + ((c.i >> 16) & 1u);   // RNE (finite inputs)
    return (unsigned short)(r >> 16);
}

// async 16B global->LDS; lds ptr must be wave-uniform (HW: base + lane*16)
#define GLL16(gp, lp) __builtin_amdgcn_global_load_lds( \
    (__attribute__((address_space(1))) void*)(gp),      \
    (__attribute__((address_space(3))) void*)(lp), 16, 0, 0)

// ---------------------------------------------------------------------------
// Weight convert + transpose: out[n*K+k] = bf16(in[k*N+n])   (out is [N,K])
// ---------------------------------------------------------------------------
__global__ __launch_bounds__(256) void wtrans(const float* __restrict__ in,
                                              unsigned short* __restrict__ out,
                                              int K, int N) {
    int idx = blockIdx.x * 256 + threadIdx.x;
    if (idx >= K * N) return;
    int n = idx / K, k = idx - n * K;
    out[idx] = f2bf(in[(size_t)k * N + n]);
}

// ---------------------------------------------------------------------------
// LayerNorm -> bf16; WINDOWED=1 adds roll(-3,-3) + window partition.
// ---------------------------------------------------------------------------
template<int WINDOWED>
__global__ __launch_bounds__(256) void ln_kernel(const float* __restrict__ x,
                                                 const float* __restrict__ gamma,
                                                 const float* __restrict__ beta,
                                                 unsigned short* __restrict__ out) {
    int wave = threadIdx.x >> 6;
    int lane = threadIdx.x & 63;
    int tok  = blockIdx.x * 4 + wave;
    int src  = tok;
    if (WINDOWED) {
        int b  = tok / (NWIN * SEQ);
        int r  = tok - b * (NWIN * SEQ);
        int wl = r / SEQ, s = r - wl * SEQ;
        int wy = wl >> 3, wx = wl & 7;
        int i  = s / WINSZ, j = s - i * WINSZ;
        int hp = wy * WINSZ + i + SHIFTSZ; if (hp >= IMG) hp -= IMG;
        int wp = wx * WINSZ + j + SHIFTSZ; if (wp >= IMG) wp -= IMG;
        src = b * (IMG * IMG) + hp * IMG + wp;
    }
    float4 v = *(const float4*)(x + (size_t)src * CDIM + lane * 4);
    float sum = v.x + v.y + v.z + v.w;
    float ss  = v.x*v.x + v.y*v.y + v.z*v.z + v.w*v.w;
#pragma unroll
    for (int off = 32; off; off >>= 1) {
        sum += __shfl_xor(sum, off);
        ss  += __shfl_xor(ss,  off);
    }
    float mu   = sum * (1.0f / CDIM);
    float var  = ss * (1.0f / CDIM) - mu * mu;
    float rstd = rsqrtf(var + EPSLN);
    float4 g  = *(const float4*)(gamma + lane * 4);
    float4 be = *(const float4*)(beta  + lane * 4);
    ushort4 o;
    o.x = f2bf((v.x - mu) * rstd * g.x + be.x);
    o.y = f2bf((v.y - mu) * rstd * g.y + be.y);
    o.z = f2bf((v.z - mu) * rstd * g.z + be.z);
    o.w = f2bf((v.w - mu) * rstd * g.w + be.w);
    *(ushort4*)(out + (size_t)tok * CDIM + lane * 4) = o;
}

// ---------------------------------------------------------------------------
// bf16 MFMA GEMM (m97 structure): C[M,N] = A[M,K] @ Bt[N,K]^T
// 128x128 tile, BK=32, 256 thr, 4 waves each 64x64 via 4x4 of 16x16x32 MFMAs.
// XOR-swizzled LDS (slot = c ^ ((r>>1)&3)) -> 2-way-max bank conflicts while
// staying global_load_lds-compatible (contiguous lane*16B destinations).
// ---------------------------------------------------------------------------
#define EPI_QKV  0
#define EPI_PROJ 1
#define EPI_MLP1 2
#define EPI_MLP2 3

template<int EPI>
__global__ __launch_bounds__(256)
void gemm_bt(const unsigned short* __restrict__ A,
             const unsigned short* __restrict__ Bt,
             int K,
             const float* __restrict__ bias,
             const float* __restrict__ resin,
             float* __restrict__ outF,
             unsigned short* __restrict__ outH) {
    __shared__ __align__(16) unsigned short As[128 * 32];
    __shared__ __align__(16) unsigned short Bs[128 * 32];
    int tid  = threadIdx.x;
    int lane = tid & 63, wave = tid >> 6;
    int q    = lane >> 4, l16 = lane & 15;
    int wm   = wave >> 1, wn = wave & 1;
    int rowBase = blockIdx.x * 128;
    int colBase = blockIdx.y * 128;

    f32x4 acc[4][4];
#pragma unroll
    for (int i = 0; i < 4; i++)
#pragma unroll
        for (int j = 0; j < 4; j++) acc[i][j] = (f32x4){0.f, 0.f, 0.f, 0.f};

    const unsigned short* Ab = A  + (size_t)rowBase * K;
    const unsigned short* Bb = Bt + (size_t)colBase * K;

    int r0 = wave * 32;                       // this wave stages tile rows [r0, r0+32)
    int ra = r0 + (lane >> 2);
    int rb = ra + 16;
    int ca = (lane & 3) ^ ((ra >> 1) & 3);    // swizzled source block
    int cb = (lane & 3) ^ ((rb >> 1) & 3);
    const size_t off1 = (size_t)ra * K + ca * 8;
    const size_t off2 = (size_t)rb * K + cb * 8;
    unsigned short* ldsA1 = &As[r0 * 32];
    unsigned short* ldsA2 = &As[(r0 + 16) * 32];
    unsigned short* ldsB1 = &Bs[r0 * 32];
    unsigned short* ldsB2 = &Bs[(r0 + 16) * 32];

    for (int k0 = 0; k0 < K; k0 += 32) {
        __syncthreads();
        GLL16(Ab + off1 + k0, ldsA1);
        GLL16(Ab + off2 + k0, ldsA2);
        GLL16(Bb + off1 + k0, ldsB1);
        GLL16(Bb + off2 + k0, ldsB2);
        __syncthreads();
        short8 af[4], bf[4];
#pragma unroll
        for (int mi = 0; mi < 4; mi++) {
            int r = wm * 64 + mi * 16 + l16;
            af[mi] = *(const short8*)&As[r * 32 + ((q ^ ((r >> 1) & 3)) * 8)];
        }
#pragma unroll
        for (int ni = 0; ni < 4; ni++) {
            int r = wn * 64 + ni * 16 + l16;
            bf[ni] = *(const short8*)&Bs[r * 32 + ((q ^ ((r >> 1) & 3)) * 8)];
        }
#pragma unroll
        for (int mi = 0; mi < 4; mi++)
#pragma unroll
            for (int ni = 0; ni < 4; ni++)
                acc[mi][ni] = __builtin_amdgcn_mfma_f32_16x16x32_bf16(
                    af[mi], bf[ni], acc[mi][ni], 0, 0, 0);
    }

    int mb = rowBase + wm * 64;
    int nb = colBase + wn * 64;

    if (EPI == EPI_QKV) {
#pragma unroll
        for (int mi = 0; mi < 4; mi++)
#pragma unroll
            for (int r = 0; r < 4; r++) {
                int m = mb + mi * 16 + q * 4 + r;
                int w = m / SEQ, s = m - w * SEQ;
#pragma unroll
                for (int ni = 0; ni < 4; ni++) {
                    int n0 = nb + ni * 16 + l16;
                    int three = n0 >> 8, hh = (n0 >> 5) & 7, dd = n0 & 31;
                    float v = acc[mi][ni][r] + bias[n0];
                    if (three == 0) v *= QSCALE;
                    outH[(size_t)three * SZT +
                         (((size_t)w * NH + hh) * SEQ + s) * DH + dd] = f2bf(v);
                }
            }
    } else if (EPI == EPI_PROJ) {
#pragma unroll
        for (int mi = 0; mi < 4; mi++)
#pragma unroll
            for (int r = 0; r < 4; r++) {
                int m = mb + mi * 16 + q * 4 + r;
                int w = m / SEQ, s = m - w * SEQ;
                int b = w >> 6, wl = w & 63;
                int wy = wl >> 3, wx = wl & 7;
                int ii = s / WINSZ, jj = s - ii * WINSZ;
                int hp = wy * WINSZ + ii + SHIFTSZ; if (hp >= IMG) hp -= IMG;
                int wp = wx * WINSZ + jj + SHIFTSZ; if (wp >= IMG) wp -= IMG;
                size_t tok = (size_t)b * (IMG * IMG) + hp * IMG + wp;
#pragma unroll
                for (int ni = 0; ni < 4; ni++) {
                    int n0 = nb + ni * 16 + l16;
                    outF[tok * CDIM + n0] = acc[mi][ni][r] + bias[n0] +
                                            resin[tok * CDIM + n0];
                }
            }
    } else if (EPI == EPI_MLP1) {
#pragma unroll
        for (int mi = 0; mi < 4; mi++)
#pragma unroll
            for (int r = 0; r < 4; r++) {
                int m = mb + mi * 16 + q * 4 + r;
#pragma unroll
                for (int ni = 0; ni < 4; ni++) {
                    int n0 = nb + ni * 16 + l16;
                    float t = acc[mi][ni][r] + bias[n0];
                    float g = 0.5f * t * (1.0f + erff(t * 0.70710678118654752f));
                    outH[(size_t)m * NMLP + n0] = f2bf(g);
                }
            }
    } else {  // EPI_MLP2
#pragma unroll
        for (int mi = 0; mi < 4; mi++)
#pragma unroll
            for (int r = 0; r < 4; r++) {
                int m = mb + mi * 16 + q * 4 + r;
#pragma unroll
                for (int ni = 0; ni < 4; ni++) {
                    int n0 = nb + ni * 16 + l16;
                    outF[(size_t)m * CDIM + n0] = acc[mi][ni][r] + bias[n0] +
                                                  resin[(size_t)m * CDIM + n0];
                }
            }
    }
}

// ---------------------------------------------------------------------------
// Attention: one block per (window, head). bf16 q/k/v in, bf16 out.
// ---------------------------------------------------------------------------
__device__ __forceinline__ int region_label(int hp, int wp) {
    if (wp >= IMG - WINSZ && wp < IMG - SHIFTSZ) return 0;  // never-written w-slice
    int lh = (hp < IMG - WINSZ) ? 0 : ((hp < IMG - SHIFTSZ) ? 1 : 2);
    int lw = (wp < IMG - WINSZ) ? 0 : 2;
    return lh * 3 + lw;
}

__global__ __launch_bounds__(256) void attn_kernel(const unsigned short* __restrict__ qkv,
                                                   const float* __restrict__ rel_tab,
                                                   unsigned short* __restrict__ outp) {
    int bx = blockIdx.x;
    int w = bx >> 3, h = bx & 7;
    __shared__ __align__(16) float lq[SEQ * 36];
    __shared__ __align__(16) float lk[SEQ * 36];
    __shared__ __align__(16) float lv[SEQ * 32];
    __shared__ __align__(16) float sc[SEQ * 50];
    __shared__ float rowmax[64], rowinv[64];
    int tid = threadIdx.x;
    const unsigned short* qg = qkv + (size_t)(w * NH + h) * SEQ * DH;
    const unsigned short* kg = qg + SZT;
    const unsigned short* vg = qg + 2 * SZT;
    for (int e = tid; e < SEQ * 4; e += 256) {
        int s = e >> 2, blk = (e & 3) * 8;
        short8 t = *(const short8*)(qg + s * DH + blk);
        float* d = lq + s * 36 + blk;
#pragma unroll
        for (int j = 0; j < 8; j++) d[j] = bf2f((unsigned short)t[j]);
    }
    for (int e = tid; e < SEQ * 4; e += 256) {
        int s = e >> 2, blk = (e & 3) * 8;
        short8 t = *(const short8*)(kg + s * DH + blk);
        float* d = lk + s * 36 + blk;
#pragma unroll
        for (int j = 0; j < 8; j++) d[j] = bf2f((unsigned short)t[j]);
    }
    for (int e = tid; e < SEQ * 4; e += 256) {
        int s = e >> 2, blk = (e & 3) * 8;
        short8 t = *(const short8*)(vg + s * DH + blk);
        float* d = lv + s * 32 + blk;
#pragma unroll
        for (int j = 0; j < 8; j++) d[j] = bf2f((unsigned short)t[j]);
    }
    int wl = w & 63;
    int wy = wl >> 3, wx = wl & 7;
    __syncthreads();
    for (int e = tid; e < SEQ * SEQ; e += 256) {
        int s = e / SEQ, t = e - s * SEQ;
        const float4* qv = (const float4*)(lq + s * 36);
        const float4* kv = (const float4*)(lk + t * 36);
        float a = 0.0f;
#pragma unroll
        for (int r = 0; r < 8; r++) {
            float4 qa = qv[r], ka = kv[r];
            a += qa.x * ka.x + qa.y * ka.y + qa.z * ka.z + qa.w * ka.w;
        }
        int is = s / WINSZ, js = s - is * WINSZ;
        int it = t / WINSZ, jt = t - it * WINSZ;
        a += rel_tab[((is - it + 6) * 13 + (js - jt + 6)) * NH + h];
        int ls = region_label(wy * WINSZ + is, wx * WINSZ + js);
        int lt = region_label(wy * WINSZ + it, wx * WINSZ + jt);
        if (ls != lt) a -= 100.0f;
        sc[s * 50 + t] = a;
    }
    __syncthreads();
    if (tid < SEQ) {
        float m = -1e30f;
        for (int t = 0; t < SEQ; t++) m = fmaxf(m, sc[tid * 50 + t]);
        rowmax[tid] = m;
    }
    __syncthreads();
    for (int e = tid; e < SEQ * SEQ; e += 256) {
        int s = e / SEQ, t = e - s * SEQ;
        sc[s * 50 + t] = expf(sc[s * 50 + t] - rowmax[s]);
    }
    __syncthreads();
    if (tid < SEQ) {
        float sm = 0.0f;
        for (int t = 0; t < SEQ; t++) sm += sc[tid * 50 + t];
        rowinv[tid] = 1.0f / sm;
    }
    __syncthreads();
    for (int e = tid; e < SEQ * DH; e += 256) {
        int s = e >> 5, d = e & 31;
        float a = 0.0f;
        for (int t = 0; t < SEQ; t++) a += sc[s * 50 + t] * lv[t * 32 + d];
        a *= rowinv[s];
        outp[((size_t)w * SEQ + s) * CDIM + h * DH + d] = f2bf(a);
    }
}

// ---------------------------------------------------------------------------
extern "C" void kernel_launch(void* const* d_in, const int* in_sizes, int n_in,
                              void* d_out, int out_size, void* d_ws, size_t ws_size,
                              hipStream_t stream) {
    const float* x      = (const float*)d_in[0];
    const float* gamma  = (const float*)d_in[1];
    const float* beta   = (const float*)d_in[2];
    const float* qkv_w  = (const float*)d_in[3];
    const float* qkv_b  = (const float*)d_in[4];
    const float* proj_w = (const float*)d_in[5];
    const float* proj_b = (const float*)d_in[6];
    const float* rel_t  = (const float*)d_in[7];
    const float* mlp_w1 = (const float*)d_in[8];
    const float* mlp_b1 = (const float*)d_in[9];
    const float* mlp_w2 = (const float*)d_in[10];
    const float* mlp_b2 = (const float*)d_in[11];
    float* outp = (float*)d_out;

    // ws layout (361.2 MB total; round-0 used 411 MB successfully):
    unsigned short* xw_bf   = (unsigned short*)d_ws;          // SZT elems (reused as xn2)
    unsigned short* qkv_bf  = xw_bf + SZT;                    // 3*SZT (q,k,v)
    unsigned short* attn_bf = qkv_bf + 3 * SZT;               // SZT
    float*          y1      = (float*)(attn_bf + SZT);        // SZT floats
    unsigned short* wt_bf   = (unsigned short*)(y1 + SZT);    // 786432 elems
    unsigned short* h_bf    = qkv_bf;                         // reuse 4*SZT region = [NTOK,1024]

    unsigned short* qkvW  = wt_bf;                 // [768,256]
    unsigned short* projW = qkvW  + 768 * 256;     // [256,256]
    unsigned short* mlp1W = projW + 256 * 256;     // [1024,256]
    unsigned short* mlp2W = mlp1W + 1024 * 256;    // [256,1024]

    wtrans<<<(768 * 256 + 255) / 256, 256, 0, stream>>>(qkv_w, qkvW, CDIM, 3 * CDIM);
    wtrans<<<(256 * 256 + 255) / 256, 256, 0, stream>>>(proj_w, projW, CDIM, CDIM);
    wtrans<<<(1024 * 256 + 255) / 256, 256, 0, stream>>>(mlp_w1, mlp1W, CDIM, NMLP);
    wtrans<<<(256 * 1024 + 255) / 256, 256, 0, stream>>>(mlp_w2, mlp2W, NMLP, CDIM);

    // 1. LN + shift + window partition -> bf16
    ln_kernel<1><<<NTOK / 4, 256, 0, stream>>>(x, gamma, beta, xw_bf);
    // 2. QKV GEMM -> q,k,v bf16 scattered
    gemm_bt<EPI_QKV><<<dim3(NTOK / 128, 6), 256, 0, stream>>>(
        xw_bf, qkvW, CDIM, qkv_b, nullptr, nullptr, qkv_bf);
    // 3. Attention -> attn_bf
    attn_kernel<<<BNW * NH, 256, 0, stream>>>(qkv_bf, rel_t, attn_bf);
    // 4. Proj + window-reverse + roll + residual -> y1 fp32
    gemm_bt<EPI_PROJ><<<dim3(NTOK / 128, 2), 256, 0, stream>>>(
        attn_bf, projW, CDIM, proj_b, x, y1, nullptr);
    // 5. LN2 -> xn2 bf16 (xw region)
    ln_kernel<0><<<NTOK / 4, 256, 0, stream>>>(y1, gamma, beta, xw_bf);
    // 6. MLP1 + GELU -> h bf16
    gemm_bt<EPI_MLP1><<<dim3(NTOK / 128, 8), 256, 0, stream>>>(
        xw_bf, mlp1W, CDIM, mlp_b1, nullptr, nullptr, h_bf);
    // 7. MLP2 + residual -> out fp32
    gemm_bt<EPI_MLP2><<<dim3(NTOK / 128, 2), 256, 0, stream>>>(
        h_bf, mlp2W, NMLP, mlp_b2, y1, outp, nullptr);
}

// Round 3
// 849.034 us; speedup vs baseline: 3.1484x; 1.0976x over previous
//
#include <hip/hip_runtime.h>
#include <math.h>

#define IMG   56
#define WINSZ 7
#define SHIFTSZ 3
#define CDIM  256
#define NH    8
#define DH    32
#define SEQ   49
#define NYW   8
#define NWIN  64
#define NMLP  1024
#define BATCH 32
#define NTOK  (BATCH*IMG*IMG)       // 100352
#define BNW   (BATCH*NWIN)          // 2048
#define SZT   ((size_t)NTOK*CDIM)   // 25,690,112
#define QSCALE 0.17677669529663687f
#define EPSLN 1e-5f

typedef __attribute__((ext_vector_type(8))) short short8;
typedef __attribute__((ext_vector_type(4))) float f32x4;

__device__ __forceinline__ float bf2f(unsigned short u) {
    union { unsigned i; float f; } c; c.i = ((unsigned)u) << 16; return c.f;
}
__device__ __forceinline__ unsigned short f2bf(float f) {
    union { float f; unsigned i; } c; c.f = f;
    unsigned r = c.i + 0x7fffu + ((c.i >> 16) & 1u);   // RNE (finite inputs)
    return (unsigned short)(r >> 16);
}

// async 16B global->LDS; lds ptr must be wave-uniform (HW: base + lane*16)
#define GLL16(gp, lp) __builtin_amdgcn_global_load_lds( \
    (__attribute__((address_space(1))) void*)(gp),      \
    (__attribute__((address_space(3))) void*)(lp), 16, 0, 0)

// ---------------------------------------------------------------------------
// Weight convert + transpose: out[n*K+k] = bf16(in[k*N+n])   (out is [N,K])
// ---------------------------------------------------------------------------
__global__ __launch_bounds__(256) void wtrans(const float* __restrict__ in,
                                              unsigned short* __restrict__ out,
                                              int K, int N) {
    int idx = blockIdx.x * 256 + threadIdx.x;
    if (idx >= K * N) return;
    int n = idx / K, k = idx - n * K;
    out[idx] = f2bf(in[(size_t)k * N + n]);
}

// ---------------------------------------------------------------------------
// LayerNorm -> bf16; WINDOWED=1 adds roll(-3,-3) + window partition.
// ---------------------------------------------------------------------------
template<int WINDOWED>
__global__ __launch_bounds__(256) void ln_kernel(const float* __restrict__ x,
                                                 const float* __restrict__ gamma,
                                                 const float* __restrict__ beta,
                                                 unsigned short* __restrict__ out) {
    int wave = threadIdx.x >> 6;
    int lane = threadIdx.x & 63;
    int tok  = blockIdx.x * 4 + wave;
    int src  = tok;
    if (WINDOWED) {
        int b  = tok / (NWIN * SEQ);
        int r  = tok - b * (NWIN * SEQ);
        int wl = r / SEQ, s = r - wl * SEQ;
        int wy = wl >> 3, wx = wl & 7;
        int i  = s / WINSZ, j = s - i * WINSZ;
        int hp = wy * WINSZ + i + SHIFTSZ; if (hp >= IMG) hp -= IMG;
        int wp = wx * WINSZ + j + SHIFTSZ; if (wp >= IMG) wp -= IMG;
        src = b * (IMG * IMG) + hp * IMG + wp;
    }
    float4 v = *(const float4*)(x + (size_t)src * CDIM + lane * 4);
    float sum = v.x + v.y + v.z + v.w;
    float ss  = v.x*v.x + v.y*v.y + v.z*v.z + v.w*v.w;
#pragma unroll
    for (int off = 32; off; off >>= 1) {
        sum += __shfl_xor(sum, off);
        ss  += __shfl_xor(ss,  off);
    }
    float mu   = sum * (1.0f / CDIM);
    float var  = ss * (1.0f / CDIM) - mu * mu;
    float rstd = rsqrtf(var + EPSLN);
    float4 g  = *(const float4*)(gamma + lane * 4);
    float4 be = *(const float4*)(beta  + lane * 4);
    ushort4 o;
    o.x = f2bf((v.x - mu) * rstd * g.x + be.x);
    o.y = f2bf((v.y - mu) * rstd * g.y + be.y);
    o.z = f2bf((v.z - mu) * rstd * g.z + be.z);
    o.w = f2bf((v.w - mu) * rstd * g.w + be.w);
    *(ushort4*)(out + (size_t)tok * CDIM + lane * 4) = o;
}

// ---------------------------------------------------------------------------
// bf16 MFMA GEMM (m97 structure): C[M,N] = A[M,K] @ Bt[N,K]^T
// ---------------------------------------------------------------------------
#define EPI_QKV  0
#define EPI_PROJ 1
#define EPI_MLP1 2
#define EPI_MLP2 3

template<int EPI>
__global__ __launch_bounds__(256)
void gemm_bt(const unsigned short* __restrict__ A,
             const unsigned short* __restrict__ Bt,
             int K,
             const float* __restrict__ bias,
             const float* __restrict__ resin,
             float* __restrict__ outF,
             unsigned short* __restrict__ outH) {
    __shared__ __align__(16) unsigned short As[128 * 32];
    __shared__ __align__(16) unsigned short Bs[128 * 32];
    int tid  = threadIdx.x;
    int lane = tid & 63, wave = tid >> 6;
    int q    = lane >> 4, l16 = lane & 15;
    int wm   = wave >> 1, wn = wave & 1;
    int rowBase = blockIdx.x * 128;
    int colBase = blockIdx.y * 128;

    f32x4 acc[4][4];
#pragma unroll
    for (int i = 0; i < 4; i++)
#pragma unroll
        for (int j = 0; j < 4; j++) acc[i][j] = (f32x4){0.f, 0.f, 0.f, 0.f};

    const unsigned short* Ab = A  + (size_t)rowBase * K;
    const unsigned short* Bb = Bt + (size_t)colBase * K;

    int r0 = wave * 32;
    int ra = r0 + (lane >> 2);
    int rb = ra + 16;
    int ca = (lane & 3) ^ ((ra >> 1) & 3);
    int cb = (lane & 3) ^ ((rb >> 1) & 3);
    const size_t off1 = (size_t)ra * K + ca * 8;
    const size_t off2 = (size_t)rb * K + cb * 8;
    unsigned short* ldsA1 = &As[r0 * 32];
    unsigned short* ldsA2 = &As[(r0 + 16) * 32];
    unsigned short* ldsB1 = &Bs[r0 * 32];
    unsigned short* ldsB2 = &Bs[(r0 + 16) * 32];

    for (int k0 = 0; k0 < K; k0 += 32) {
        __syncthreads();
        GLL16(Ab + off1 + k0, ldsA1);
        GLL16(Ab + off2 + k0, ldsA2);
        GLL16(Bb + off1 + k0, ldsB1);
        GLL16(Bb + off2 + k0, ldsB2);
        __syncthreads();
        short8 af[4], bf[4];
#pragma unroll
        for (int mi = 0; mi < 4; mi++) {
            int r = wm * 64 + mi * 16 + l16;
            af[mi] = *(const short8*)&As[r * 32 + ((q ^ ((r >> 1) & 3)) * 8)];
        }
#pragma unroll
        for (int ni = 0; ni < 4; ni++) {
            int r = wn * 64 + ni * 16 + l16;
            bf[ni] = *(const short8*)&Bs[r * 32 + ((q ^ ((r >> 1) & 3)) * 8)];
        }
#pragma unroll
        for (int mi = 0; mi < 4; mi++)
#pragma unroll
            for (int ni = 0; ni < 4; ni++)
                acc[mi][ni] = __builtin_amdgcn_mfma_f32_16x16x32_bf16(
                    af[mi], bf[ni], acc[mi][ni], 0, 0, 0);
    }

    int mb = rowBase + wm * 64;
    int nb = colBase + wn * 64;

    if (EPI == EPI_QKV) {
#pragma unroll
        for (int mi = 0; mi < 4; mi++)
#pragma unroll
            for (int r = 0; r < 4; r++) {
                int m = mb + mi * 16 + q * 4 + r;
                int w = m / SEQ, s = m - w * SEQ;
#pragma unroll
                for (int ni = 0; ni < 4; ni++) {
                    int n0 = nb + ni * 16 + l16;
                    int three = n0 >> 8, hh = (n0 >> 5) & 7, dd = n0 & 31;
                    float v = acc[mi][ni][r] + bias[n0];
                    if (three == 0) {
                        v *= QSCALE;
                        outH[(((size_t)w * NH + hh) * SEQ + s) * DH + dd] = f2bf(v);
                    } else if (three == 1) {
                        outH[SZT + (((size_t)w * NH + hh) * SEQ + s) * DH + dd] = f2bf(v);
                    } else {
                        // V transposed+padded: [w,h,d,64], col t=s
                        outH[2 * SZT + (((size_t)w * NH + hh) * DH + dd) * 64 + s] = f2bf(v);
                    }
                }
            }
    } else if (EPI == EPI_PROJ) {
#pragma unroll
        for (int mi = 0; mi < 4; mi++)
#pragma unroll
            for (int r = 0; r < 4; r++) {
                int m = mb + mi * 16 + q * 4 + r;
                int w = m / SEQ, s = m - w * SEQ;
                int b = w >> 6, wl = w & 63;
                int wy = wl >> 3, wx = wl & 7;
                int ii = s / WINSZ, jj = s - ii * WINSZ;
                int hp = wy * WINSZ + ii + SHIFTSZ; if (hp >= IMG) hp -= IMG;
                int wp = wx * WINSZ + jj + SHIFTSZ; if (wp >= IMG) wp -= IMG;
                size_t tok = (size_t)b * (IMG * IMG) + hp * IMG + wp;
#pragma unroll
                for (int ni = 0; ni < 4; ni++) {
                    int n0 = nb + ni * 16 + l16;
                    outF[tok * CDIM + n0] = acc[mi][ni][r] + bias[n0] +
                                            resin[tok * CDIM + n0];
                }
            }
    } else if (EPI == EPI_MLP1) {
#pragma unroll
        for (int mi = 0; mi < 4; mi++)
#pragma unroll
            for (int r = 0; r < 4; r++) {
                int m = mb + mi * 16 + q * 4 + r;
#pragma unroll
                for (int ni = 0; ni < 4; ni++) {
                    int n0 = nb + ni * 16 + l16;
                    float t = acc[mi][ni][r] + bias[n0];
                    float g = 0.5f * t * (1.0f + erff(t * 0.70710678118654752f));
                    outH[(size_t)m * NMLP + n0] = f2bf(g);
                }
            }
    } else {  // EPI_MLP2
#pragma unroll
        for (int mi = 0; mi < 4; mi++)
#pragma unroll
            for (int r = 0; r < 4; r++) {
                int m = mb + mi * 16 + q * 4 + r;
#pragma unroll
                for (int ni = 0; ni < 4; ni++) {
                    int n0 = nb + ni * 16 + l16;
                    outF[(size_t)m * CDIM + n0] = acc[mi][ni][r] + bias[n0] +
                                                  resin[(size_t)m * CDIM + n0];
                }
            }
    }
}

// ---------------------------------------------------------------------------
// MFMA attention: one WAVE per (window, head). 4 waves/block, 4096 blocks.
// QK^T: 64x64x32 = 16 MFMAs. Softmax in registers (shfl over l16).
// P -> LDS (XOR-swizzled) -> A-frags. PV: 64x32x64 = 16 MFMAs.
// V comes pre-transposed+padded [w,h,d,64] from the QKV epilogue.
// ---------------------------------------------------------------------------
__global__ __launch_bounds__(256) void attn_mfma(const unsigned short* __restrict__ qb,
                                                 const unsigned short* __restrict__ kb,
                                                 const unsigned short* __restrict__ vT,
                                                 const float* __restrict__ rel_tab,
                                                 unsigned short* __restrict__ outp) {
    __shared__ __align__(16) unsigned short Pl[4][64 * 64];
    __shared__ float tab[4][169];
    int tid  = threadIdx.x;
    int wave = tid >> 6, lane = tid & 63;
    int q4   = lane >> 4, l16 = lane & 15;
    int job  = blockIdx.x * 4 + wave;
    int w    = job >> 3, h = job & 7;

    for (int i = lane; i < 169; i += 64) tab[wave][i] = rel_tab[i * NH + h];

    const unsigned short* qg = qb + (size_t)(w * NH + h) * SEQ * DH;
    const unsigned short* kg = kb + (size_t)(w * NH + h) * SEQ * DH;
    short8 aq[4], bk[4];
#pragma unroll
    for (int mi = 0; mi < 4; mi++)
        aq[mi] = *(const short8*)(qg + (mi * 16 + l16) * DH + q4 * 8);
#pragma unroll
    for (int ni = 0; ni < 4; ni++)
        bk[ni] = *(const short8*)(kg + (ni * 16 + l16) * DH + q4 * 8);

    f32x4 acc[4][4];
#pragma unroll
    for (int i = 0; i < 4; i++)
#pragma unroll
        for (int j = 0; j < 4; j++) acc[i][j] = (f32x4){0.f, 0.f, 0.f, 0.f};
#pragma unroll
    for (int mi = 0; mi < 4; mi++)
#pragma unroll
        for (int ni = 0; ni < 4; ni++)
            acc[mi][ni] = __builtin_amdgcn_mfma_f32_16x16x32_bf16(
                aq[mi], bk[ni], acc[mi][ni], 0, 0, 0);

    int wl = w & 63;
    int wy = wl >> 3, wx = wl & 7;
    bool edge = (wy == 7) || (wx == 7);

    int itv[4], jtv[4], ltv[4];
#pragma unroll
    for (int ni = 0; ni < 4; ni++) {
        int t  = ni * 16 + l16;
        int it = (t * 37) >> 8;
        int jt = t - it * 7;
        itv[ni] = it; jtv[ni] = jt;
        int lab;
        if (wx == 7 && jt < 4) lab = 0;       // the never-written w-slice quirk
        else {
            int lh = (wy == 7) ? ((it < 4) ? 1 : 2) : 0;
            lab = lh * 3 + ((wx == 7) ? 2 : 0);
        }
        ltv[ni] = lab;
    }

    float rinv[4][4];
#pragma unroll
    for (int mi = 0; mi < 4; mi++) {
#pragma unroll
        for (int r = 0; r < 4; r++) {
            int s  = mi * 16 + q4 * 4 + r;
            int is = (s * 37) >> 8;
            int js = s - is * 7;
            int lab_s;
            if (wx == 7 && js < 4) lab_s = 0;
            else {
                int lh = (wy == 7) ? ((is < 4) ? 1 : 2) : 0;
                lab_s = lh * 3 + ((wx == 7) ? 2 : 0);
            }
            float vv[4];
#pragma unroll
            for (int ni = 0; ni < 4; ni++) {
                int t = ni * 16 + l16;
                float a = acc[mi][ni][r];
                if (t < SEQ) {
                    int idx = (is - itv[ni] + 6) * 13 + (js - jtv[ni] + 6);
                    idx = idx < 0 ? 0 : (idx > 168 ? 168 : idx);
                    a += tab[wave][idx];
                    if (edge && lab_s != ltv[ni]) a -= 100.0f;
                } else {
                    a = -1e30f;
                }
                vv[ni] = a;
            }
            float mx = fmaxf(fmaxf(vv[0], vv[1]), fmaxf(vv[2], vv[3]));
#pragma unroll
            for (int off = 1; off < 16; off <<= 1) mx = fmaxf(mx, __shfl_xor(mx, off));
            float sm = 0.0f;
            unsigned short pb[4];
#pragma unroll
            for (int ni = 0; ni < 4; ni++) {
                float p = __expf(vv[ni] - mx);
                sm += p;
                pb[ni] = f2bf(p);
            }
#pragma unroll
            for (int off = 1; off < 16; off <<= 1) sm += __shfl_xor(sm, off);
            rinv[mi][r] = 1.0f / sm;
#pragma unroll
            for (int ni = 0; ni < 4; ni++) {
                int t  = ni * 16 + l16;
                int kbk = t >> 3, j = t & 7;
                Pl[wave][s * 64 + ((kbk ^ (s & 7)) * 8) + j] = pb[ni];
            }
        }
    }
    __syncthreads();

    short8 pa[4][2];
#pragma unroll
    for (int mi = 0; mi < 4; mi++)
#pragma unroll
        for (int ks = 0; ks < 2; ks++) {
            int m  = mi * 16 + l16;
            int kbk = ks * 4 + q4;
            pa[mi][ks] = *(const short8*)&Pl[wave][m * 64 + ((kbk ^ (m & 7)) * 8)];
        }
    const unsigned short* vg = vT + (size_t)(w * NH + h) * DH * 64;
    short8 bv[2][2];
#pragma unroll
    for (int n2 = 0; n2 < 2; n2++)
#pragma unroll
        for (int ks = 0; ks < 2; ks++)
            bv[n2][ks] = *(const short8*)(vg + (n2 * 16 + l16) * 64 + ks * 32 + q4 * 8);

    f32x4 o[4][2];
#pragma unroll
    for (int mi = 0; mi < 4; mi++)
#pragma unroll
        for (int n2 = 0; n2 < 2; n2++) o[mi][n2] = (f32x4){0.f, 0.f, 0.f, 0.f};
#pragma unroll
    for (int ks = 0; ks < 2; ks++)
#pragma unroll
        for (int mi = 0; mi < 4; mi++)
#pragma unroll
            for (int n2 = 0; n2 < 2; n2++)
                o[mi][n2] = __builtin_amdgcn_mfma_f32_16x16x32_bf16(
                    pa[mi][ks], bv[n2][ks], o[mi][n2], 0, 0, 0);

#pragma unroll
    for (int mi = 0; mi < 4; mi++)
#pragma unroll
        for (int r = 0; r < 4; r++) {
            int s = mi * 16 + q4 * 4 + r;
            if (s < SEQ) {
#pragma unroll
                for (int n2 = 0; n2 < 2; n2++) {
                    int d = n2 * 16 + l16;
                    outp[((size_t)w * SEQ + s) * CDIM + h * DH + d] =
                        f2bf(o[mi][n2][r] * rinv[mi][r]);
                }
            }
        }
}

// ---------------------------------------------------------------------------
extern "C" void kernel_launch(void* const* d_in, const int* in_sizes, int n_in,
                              void* d_out, int out_size, void* d_ws, size_t ws_size,
                              hipStream_t stream) {
    const float* x      = (const float*)d_in[0];
    const float* gamma  = (const float*)d_in[1];
    const float* beta   = (const float*)d_in[2];
    const float* qkv_w  = (const float*)d_in[3];
    const float* qkv_b  = (const float*)d_in[4];
    const float* proj_w = (const float*)d_in[5];
    const float* proj_b = (const float*)d_in[6];
    const float* rel_t  = (const float*)d_in[7];
    const float* mlp_w1 = (const float*)d_in[8];
    const float* mlp_b1 = (const float*)d_in[9];
    const float* mlp_w2 = (const float*)d_in[10];
    const float* mlp_b2 = (const float*)d_in[11];
    float* outp = (float*)d_out;

    const size_t VTSZ = (size_t)BNW * NH * DH * 64;   // 33,554,432
    unsigned short* xw_bf   = (unsigned short*)d_ws;              // SZT
    unsigned short* qkv_bf  = xw_bf + SZT;                        // q:SZT, k:SZT, vT:VTSZ
    unsigned short* attn_bf = qkv_bf + 2 * SZT + VTSZ;            // SZT
    float*          y1      = (float*)(attn_bf + SZT);            // SZT floats
    unsigned short* wt_bf   = (unsigned short*)(y1 + SZT);        // 786432
    unsigned short* h_bf    = qkv_bf;   // reuse q+k+vT+attn (>= NTOK*NMLP)

    unsigned short* qkvW  = wt_bf;
    unsigned short* projW = qkvW  + 768 * 256;
    unsigned short* mlp1W = projW + 256 * 256;
    unsigned short* mlp2W = mlp1W + 1024 * 256;

    wtrans<<<(768 * 256 + 255) / 256, 256, 0, stream>>>(qkv_w, qkvW, CDIM, 3 * CDIM);
    wtrans<<<(256 * 256 + 255) / 256, 256, 0, stream>>>(proj_w, projW, CDIM, CDIM);
    wtrans<<<(1024 * 256 + 255) / 256, 256, 0, stream>>>(mlp_w1, mlp1W, CDIM, NMLP);
    wtrans<<<(256 * 1024 + 255) / 256, 256, 0, stream>>>(mlp_w2, mlp2W, NMLP, CDIM);

    ln_kernel<1><<<NTOK / 4, 256, 0, stream>>>(x, gamma, beta, xw_bf);
    gemm_bt<EPI_QKV><<<dim3(NTOK / 128, 6), 256, 0, stream>>>(
        xw_bf, qkvW, CDIM, qkv_b, nullptr, nullptr, qkv_bf);
    attn_mfma<<<BNW * NH / 4, 256, 0, stream>>>(
        qkv_bf, qkv_bf + SZT, qkv_bf + 2 * SZT, rel_t, attn_bf);
    gemm_bt<EPI_PROJ><<<dim3(NTOK / 128, 2), 256, 0, stream>>>(
        attn_bf, projW, CDIM, proj_b, x, y1, nullptr);
    ln_kernel<0><<<NTOK / 4, 256, 0, stream>>>(y1, gamma, beta, xw_bf);
    gemm_bt<EPI_MLP1><<<dim3(NTOK / 128, 8), 256, 0, stream>>>(
        xw_bf, mlp1W, CDIM, mlp_b1, nullptr, nullptr, h_bf);
    gemm_bt<EPI_MLP2><<<dim3(NTOK / 128, 2), 256, 0, stream>>>(
        h_bf, mlp2W, NMLP, mlp_b2, y1, outp, nullptr);
}

// Round 4
// 757.961 us; speedup vs baseline: 3.5267x; 1.1202x over previous
//
#include <hip/hip_runtime.h>
#include <math.h>

#define IMG   56
#define WINSZ 7
#define SHIFTSZ 3
#define CDIM  256
#define NH    8
#define DH    32
#define SEQ   49
#define NYW   8
#define NWIN  64
#define NMLP  1024
#define BATCH 32
#define NTOK  (BATCH*IMG*IMG)       // 100352
#define BNW   (BATCH*NWIN)          // 2048
#define SZT   ((size_t)NTOK*CDIM)   // 25,690,112
#define QSCALE 0.17677669529663687f
#define EPSLN 1e-5f

typedef __attribute__((ext_vector_type(8))) short short8;
typedef __attribute__((ext_vector_type(4))) float f32x4;

__device__ __forceinline__ float bf2f(unsigned short u) {
    union { unsigned i; float f; } c; c.i = ((unsigned)u) << 16; return c.f;
}
__device__ __forceinline__ unsigned short f2bf(float f) {
    union { float f; unsigned i; } c; c.f = f;
    unsigned r = c.i + 0x7fffu + ((c.i >> 16) & 1u);   // RNE (finite inputs)
    return (unsigned short)(r >> 16);
}

// fast erf-based exact-GELU: A&S 7.1.26, |erf err| <= 1.5e-7 (<< bf16 ulp)
__device__ __forceinline__ float gelu_f(float v) {
    float u = v * 0.70710678118654752f;
    float x = fabsf(u);
    float t = __builtin_amdgcn_rcpf(fmaf(0.3275911f, x, 1.0f));
    float e = __expf(-u * u);
    float p = fmaf(1.061405429f, t, -1.453152027f);
    p = fmaf(p, t, 1.421413741f);
    p = fmaf(p, t, -0.284496736f);
    p = fmaf(p, t, 0.254829592f);
    float er = 1.0f - p * t * e;
    er = copysignf(er, u);
    return 0.5f * v * (1.0f + er);
}

// async 16B global->LDS; lds ptr must be wave-uniform (HW: base + lane*16)
#define GLL16(gp, lp) __builtin_amdgcn_global_load_lds( \
    (__attribute__((address_space(1))) void*)(gp),      \
    (__attribute__((address_space(3))) void*)(lp), 16, 0, 0)

// ---------------------------------------------------------------------------
// Weight convert + transpose: out[n*K+k] = bf16(in[k*N+n])   (out is [N,K])
// ---------------------------------------------------------------------------
__global__ __launch_bounds__(256) void wtrans(const float* __restrict__ in,
                                              unsigned short* __restrict__ out,
                                              int K, int N) {
    int idx = blockIdx.x * 256 + threadIdx.x;
    if (idx >= K * N) return;
    int n = idx / K, k = idx - n * K;
    out[idx] = f2bf(in[(size_t)k * N + n]);
}

// ---------------------------------------------------------------------------
// LayerNorm -> bf16; WINDOWED=1 adds roll(-3,-3) + window partition.
// ---------------------------------------------------------------------------
template<int WINDOWED>
__global__ __launch_bounds__(256) void ln_kernel(const float* __restrict__ x,
                                                 const float* __restrict__ gamma,
                                                 const float* __restrict__ beta,
                                                 unsigned short* __restrict__ out) {
    int wave = threadIdx.x >> 6;
    int lane = threadIdx.x & 63;
    int tok  = blockIdx.x * 4 + wave;
    int src  = tok;
    if (WINDOWED) {
        int b  = tok / (NWIN * SEQ);
        int r  = tok - b * (NWIN * SEQ);
        int wl = r / SEQ, s = r - wl * SEQ;
        int wy = wl >> 3, wx = wl & 7;
        int i  = s / WINSZ, j = s - i * WINSZ;
        int hp = wy * WINSZ + i + SHIFTSZ; if (hp >= IMG) hp -= IMG;
        int wp = wx * WINSZ + j + SHIFTSZ; if (wp >= IMG) wp -= IMG;
        src = b * (IMG * IMG) + hp * IMG + wp;
    }
    float4 v = *(const float4*)(x + (size_t)src * CDIM + lane * 4);
    float sum = v.x + v.y + v.z + v.w;
    float ss  = v.x*v.x + v.y*v.y + v.z*v.z + v.w*v.w;
#pragma unroll
    for (int off = 32; off; off >>= 1) {
        sum += __shfl_xor(sum, off);
        ss  += __shfl_xor(ss,  off);
    }
    float mu   = sum * (1.0f / CDIM);
    float var  = ss * (1.0f / CDIM) - mu * mu;
    float rstd = rsqrtf(var + EPSLN);
    float4 g  = *(const float4*)(gamma + lane * 4);
    float4 be = *(const float4*)(beta  + lane * 4);
    ushort4 o;
    o.x = f2bf((v.x - mu) * rstd * g.x + be.x);
    o.y = f2bf((v.y - mu) * rstd * g.y + be.y);
    o.z = f2bf((v.z - mu) * rstd * g.z + be.z);
    o.w = f2bf((v.w - mu) * rstd * g.w + be.w);
    *(ushort4*)(out + (size_t)tok * CDIM + lane * 4) = o;
}

// ---------------------------------------------------------------------------
// bf16 MFMA GEMM: C[M,N] = A[M,K] @ Bt[N,K]^T.
// SWAPPED operand order: mfma(bf, af) -> D cols(l16)=m, rows(q4*4+r)=n,
// so each lane holds 4 consecutive n at fixed m -> packed epilogue stores.
// Grid: x = column blocks (fastest) for L2 A-tile reuse, y = row blocks.
// ---------------------------------------------------------------------------
#define EPI_QKV  0
#define EPI_PROJ 1
#define EPI_MLP1 2
#define EPI_MLP2 3

template<int EPI>
__global__ __launch_bounds__(256)
void gemm_bt(const unsigned short* __restrict__ A,
             const unsigned short* __restrict__ Bt,
             int K,
             const float* __restrict__ bias,
             const float* __restrict__ resin,
             float* __restrict__ outF,
             unsigned short* __restrict__ outH) {
    __shared__ __align__(16) unsigned short As[128 * 32];
    __shared__ __align__(16) unsigned short Bs[128 * 32];
    int tid  = threadIdx.x;
    int lane = tid & 63, wave = tid >> 6;
    int q4   = lane >> 4, l16 = lane & 15;
    int wm   = wave >> 1, wn = wave & 1;
    int rowBase = blockIdx.y * 128;
    int colBase = blockIdx.x * 128;

    f32x4 acc[4][4];
#pragma unroll
    for (int i = 0; i < 4; i++)
#pragma unroll
        for (int j = 0; j < 4; j++) acc[i][j] = (f32x4){0.f, 0.f, 0.f, 0.f};

    const unsigned short* Ab = A  + (size_t)rowBase * K;
    const unsigned short* Bb = Bt + (size_t)colBase * K;

    int r0 = wave * 32;
    int ra = r0 + (lane >> 2);
    int rb = ra + 16;
    int ca = (lane & 3) ^ ((ra >> 1) & 3);
    int cb = (lane & 3) ^ ((rb >> 1) & 3);
    const size_t off1 = (size_t)ra * K + ca * 8;
    const size_t off2 = (size_t)rb * K + cb * 8;
    unsigned short* ldsA1 = &As[r0 * 32];
    unsigned short* ldsA2 = &As[(r0 + 16) * 32];
    unsigned short* ldsB1 = &Bs[r0 * 32];
    unsigned short* ldsB2 = &Bs[(r0 + 16) * 32];

    for (int k0 = 0; k0 < K; k0 += 32) {
        __syncthreads();
        GLL16(Ab + off1 + k0, ldsA1);
        GLL16(Ab + off2 + k0, ldsA2);
        GLL16(Bb + off1 + k0, ldsB1);
        GLL16(Bb + off2 + k0, ldsB2);
        __syncthreads();
        short8 af[4], bf[4];
#pragma unroll
        for (int mi = 0; mi < 4; mi++) {
            int r = wm * 64 + mi * 16 + l16;
            af[mi] = *(const short8*)&As[r * 32 + ((q4 ^ ((r >> 1) & 3)) * 8)];
        }
#pragma unroll
        for (int ni = 0; ni < 4; ni++) {
            int r = wn * 64 + ni * 16 + l16;
            bf[ni] = *(const short8*)&Bs[r * 32 + ((q4 ^ ((r >> 1) & 3)) * 8)];
        }
#pragma unroll
        for (int mi = 0; mi < 4; mi++)
#pragma unroll
            for (int ni = 0; ni < 4; ni++)
                acc[mi][ni] = __builtin_amdgcn_mfma_f32_16x16x32_bf16(
                    bf[ni], af[mi], acc[mi][ni], 0, 0, 0);   // swapped operands
    }

    int mb = rowBase + wm * 64;
    int nb = colBase + wn * 64;
    float4 bias4[4];
#pragma unroll
    for (int ni = 0; ni < 4; ni++)
        bias4[ni] = *(const float4*)(bias + nb + ni * 16 + q4 * 4);

    if (EPI == EPI_QKV) {
        int three = colBase >> 8;   // uniform per block: 0=q, 1=k, 2=v
#pragma unroll
        for (int mi = 0; mi < 4; mi++) {
            int m = mb + mi * 16 + l16;
            int w = m / SEQ, s = m - w * SEQ;
#pragma unroll
            for (int ni = 0; ni < 4; ni++) {
                int n0 = nb + ni * 16 + q4 * 4;
                int hh = (n0 >> 5) & 7, dd0 = n0 & 31;
                const float* bp = (const float*)&bias4[ni];
                if (three == 2) {
#pragma unroll
                    for (int r = 0; r < 4; r++)
                        outH[2 * SZT + (((size_t)(w * NH + hh)) * DH + dd0 + r) * 64 + s] =
                            f2bf(acc[mi][ni][r] + bp[r]);
                } else {
                    float sc = (three == 0) ? QSCALE : 1.0f;
                    ushort4 o;
                    o.x = f2bf((acc[mi][ni][0] + bp[0]) * sc);
                    o.y = f2bf((acc[mi][ni][1] + bp[1]) * sc);
                    o.z = f2bf((acc[mi][ni][2] + bp[2]) * sc);
                    o.w = f2bf((acc[mi][ni][3] + bp[3]) * sc);
                    *(ushort4*)(outH + (size_t)three * SZT +
                                (((size_t)(w * NH + hh)) * SEQ + s) * DH + dd0) = o;
                }
            }
        }
    } else if (EPI == EPI_PROJ) {
#pragma unroll
        for (int mi = 0; mi < 4; mi++) {
            int m = mb + mi * 16 + l16;
            int w = m / SEQ, s = m - w * SEQ;
            int b = w >> 6, wl = w & 63;
            int wy = wl >> 3, wx = wl & 7;
            int ii = s / WINSZ, jj = s - ii * WINSZ;
            int hp = wy * WINSZ + ii + SHIFTSZ; if (hp >= IMG) hp -= IMG;
            int wp = wx * WINSZ + jj + SHIFTSZ; if (wp >= IMG) wp -= IMG;
            size_t tok = (size_t)b * (IMG * IMG) + hp * IMG + wp;
#pragma unroll
            for (int ni = 0; ni < 4; ni++) {
                int n0 = nb + ni * 16 + q4 * 4;
                float4 res = *(const float4*)(resin + tok * CDIM + n0);
                float4 o;
                o.x = acc[mi][ni][0] + bias4[ni].x + res.x;
                o.y = acc[mi][ni][1] + bias4[ni].y + res.y;
                o.z = acc[mi][ni][2] + bias4[ni].z + res.z;
                o.w = acc[mi][ni][3] + bias4[ni].w + res.w;
                *(float4*)(outF + tok * CDIM + n0) = o;
            }
        }
    } else if (EPI == EPI_MLP1) {
#pragma unroll
        for (int mi = 0; mi < 4; mi++) {
            int m = mb + mi * 16 + l16;
#pragma unroll
            for (int ni = 0; ni < 4; ni++) {
                int n0 = nb + ni * 16 + q4 * 4;
                ushort4 o;
                o.x = f2bf(gelu_f(acc[mi][ni][0] + bias4[ni].x));
                o.y = f2bf(gelu_f(acc[mi][ni][1] + bias4[ni].y));
                o.z = f2bf(gelu_f(acc[mi][ni][2] + bias4[ni].z));
                o.w = f2bf(gelu_f(acc[mi][ni][3] + bias4[ni].w));
                *(ushort4*)(outH + (size_t)m * NMLP + n0) = o;
            }
        }
    } else {  // EPI_MLP2
#pragma unroll
        for (int mi = 0; mi < 4; mi++) {
            int m = mb + mi * 16 + l16;
#pragma unroll
            for (int ni = 0; ni < 4; ni++) {
                int n0 = nb + ni * 16 + q4 * 4;
                float4 res = *(const float4*)(resin + (size_t)m * CDIM + n0);
                float4 o;
                o.x = acc[mi][ni][0] + bias4[ni].x + res.x;
                o.y = acc[mi][ni][1] + bias4[ni].y + res.y;
                o.z = acc[mi][ni][2] + bias4[ni].z + res.z;
                o.w = acc[mi][ni][3] + bias4[ni].w + res.w;
                *(float4*)(outF + (size_t)m * CDIM + n0) = o;
            }
        }
    }
}

// ---------------------------------------------------------------------------
// MFMA attention: one WAVE per (window, head). Unchanged from round 3.
// ---------------------------------------------------------------------------
__global__ __launch_bounds__(256) void attn_mfma(const unsigned short* __restrict__ qb,
                                                 const unsigned short* __restrict__ kb,
                                                 const unsigned short* __restrict__ vT,
                                                 const float* __restrict__ rel_tab,
                                                 unsigned short* __restrict__ outp) {
    __shared__ __align__(16) unsigned short Pl[4][64 * 64];
    __shared__ float tab[4][169];
    int tid  = threadIdx.x;
    int wave = tid >> 6, lane = tid & 63;
    int q4   = lane >> 4, l16 = lane & 15;
    int job  = blockIdx.x * 4 + wave;
    int w    = job >> 3, h = job & 7;

    for (int i = lane; i < 169; i += 64) tab[wave][i] = rel_tab[i * NH + h];

    const unsigned short* qg = qb + (size_t)(w * NH + h) * SEQ * DH;
    const unsigned short* kg = kb + (size_t)(w * NH + h) * SEQ * DH;
    short8 aq[4], bk[4];
#pragma unroll
    for (int mi = 0; mi < 4; mi++)
        aq[mi] = *(const short8*)(qg + (mi * 16 + l16) * DH + q4 * 8);
#pragma unroll
    for (int ni = 0; ni < 4; ni++)
        bk[ni] = *(const short8*)(kg + (ni * 16 + l16) * DH + q4 * 8);

    f32x4 acc[4][4];
#pragma unroll
    for (int i = 0; i < 4; i++)
#pragma unroll
        for (int j = 0; j < 4; j++) acc[i][j] = (f32x4){0.f, 0.f, 0.f, 0.f};
#pragma unroll
    for (int mi = 0; mi < 4; mi++)
#pragma unroll
        for (int ni = 0; ni < 4; ni++)
            acc[mi][ni] = __builtin_amdgcn_mfma_f32_16x16x32_bf16(
                aq[mi], bk[ni], acc[mi][ni], 0, 0, 0);

    int wl = w & 63;
    int wy = wl >> 3, wx = wl & 7;
    bool edge = (wy == 7) || (wx == 7);

    int itv[4], jtv[4], ltv[4];
#pragma unroll
    for (int ni = 0; ni < 4; ni++) {
        int t  = ni * 16 + l16;
        int it = (t * 37) >> 8;
        int jt = t - it * 7;
        itv[ni] = it; jtv[ni] = jt;
        int lab;
        if (wx == 7 && jt < 4) lab = 0;
        else {
            int lh = (wy == 7) ? ((it < 4) ? 1 : 2) : 0;
            lab = lh * 3 + ((wx == 7) ? 2 : 0);
        }
        ltv[ni] = lab;
    }

    float rinv[4][4];
#pragma unroll
    for (int mi = 0; mi < 4; mi++) {
#pragma unroll
        for (int r = 0; r < 4; r++) {
            int s  = mi * 16 + q4 * 4 + r;
            int is = (s * 37) >> 8;
            int js = s - is * 7;
            int lab_s;
            if (wx == 7 && js < 4) lab_s = 0;
            else {
                int lh = (wy == 7) ? ((is < 4) ? 1 : 2) : 0;
                lab_s = lh * 3 + ((wx == 7) ? 2 : 0);
            }
            float vv[4];
#pragma unroll
            for (int ni = 0; ni < 4; ni++) {
                int t = ni * 16 + l16;
                float a = acc[mi][ni][r];
                if (t < SEQ) {
                    int idx = (is - itv[ni] + 6) * 13 + (js - jtv[ni] + 6);
                    idx = idx < 0 ? 0 : (idx > 168 ? 168 : idx);
                    a += tab[wave][idx];
                    if (edge && lab_s != ltv[ni]) a -= 100.0f;
                } else {
                    a = -1e30f;
                }
                vv[ni] = a;
            }
            float mx = fmaxf(fmaxf(vv[0], vv[1]), fmaxf(vv[2], vv[3]));
#pragma unroll
            for (int off = 1; off < 16; off <<= 1) mx = fmaxf(mx, __shfl_xor(mx, off));
            float sm = 0.0f;
            unsigned short pb[4];
#pragma unroll
            for (int ni = 0; ni < 4; ni++) {
                float p = __expf(vv[ni] - mx);
                sm += p;
                pb[ni] = f2bf(p);
            }
#pragma unroll
            for (int off = 1; off < 16; off <<= 1) sm += __shfl_xor(sm, off);
            rinv[mi][r] = 1.0f / sm;
#pragma unroll
            for (int ni = 0; ni < 4; ni++) {
                int t  = ni * 16 + l16;
                int kbk = t >> 3, j = t & 7;
                Pl[wave][s * 64 + ((kbk ^ (s & 7)) * 8) + j] = pb[ni];
            }
        }
    }
    __syncthreads();

    short8 pa[4][2];
#pragma unroll
    for (int mi = 0; mi < 4; mi++)
#pragma unroll
        for (int ks = 0; ks < 2; ks++) {
            int m  = mi * 16 + l16;
            int kbk = ks * 4 + q4;
            pa[mi][ks] = *(const short8*)&Pl[wave][m * 64 + ((kbk ^ (m & 7)) * 8)];
        }
    const unsigned short* vg = vT + (size_t)(w * NH + h) * DH * 64;
    short8 bv[2][2];
#pragma unroll
    for (int n2 = 0; n2 < 2; n2++)
#pragma unroll
        for (int ks = 0; ks < 2; ks++)
            bv[n2][ks] = *(const short8*)(vg + (n2 * 16 + l16) * 64 + ks * 32 + q4 * 8);

    f32x4 o[4][2];
#pragma unroll
    for (int mi = 0; mi < 4; mi++)
#pragma unroll
        for (int n2 = 0; n2 < 2; n2++) o[mi][n2] = (f32x4){0.f, 0.f, 0.f, 0.f};
#pragma unroll
    for (int ks = 0; ks < 2; ks++)
#pragma unroll
        for (int mi = 0; mi < 4; mi++)
#pragma unroll
            for (int n2 = 0; n2 < 2; n2++)
                o[mi][n2] = __builtin_amdgcn_mfma_f32_16x16x32_bf16(
                    pa[mi][ks], bv[n2][ks], o[mi][n2], 0, 0, 0);

#pragma unroll
    for (int mi = 0; mi < 4; mi++)
#pragma unroll
        for (int r = 0; r < 4; r++) {
            int s = mi * 16 + q4 * 4 + r;
            if (s < SEQ) {
#pragma unroll
                for (int n2 = 0; n2 < 2; n2++) {
                    int d = n2 * 16 + l16;
                    outp[((size_t)w * SEQ + s) * CDIM + h * DH + d] =
                        f2bf(o[mi][n2][r] * rinv[mi][r]);
                }
            }
        }
}

// ---------------------------------------------------------------------------
extern "C" void kernel_launch(void* const* d_in, const int* in_sizes, int n_in,
                              void* d_out, int out_size, void* d_ws, size_t ws_size,
                              hipStream_t stream) {
    const float* x      = (const float*)d_in[0];
    const float* gamma  = (const float*)d_in[1];
    const float* beta   = (const float*)d_in[2];
    const float* qkv_w  = (const float*)d_in[3];
    const float* qkv_b  = (const float*)d_in[4];
    const float* proj_w = (const float*)d_in[5];
    const float* proj_b = (const float*)d_in[6];
    const float* rel_t  = (const float*)d_in[7];
    const float* mlp_w1 = (const float*)d_in[8];
    const float* mlp_b1 = (const float*)d_in[9];
    const float* mlp_w2 = (const float*)d_in[10];
    const float* mlp_b2 = (const float*)d_in[11];
    float* outp = (float*)d_out;

    const size_t VTSZ = (size_t)BNW * NH * DH * 64;   // 33,554,432
    unsigned short* xw_bf   = (unsigned short*)d_ws;              // SZT
    unsigned short* qkv_bf  = xw_bf + SZT;                        // q:SZT, k:SZT, vT:VTSZ
    unsigned short* attn_bf = qkv_bf + 2 * SZT + VTSZ;            // SZT
    float*          y1      = (float*)(attn_bf + SZT);            // SZT floats
    unsigned short* wt_bf   = (unsigned short*)(y1 + SZT);        // 786432
    unsigned short* h_bf    = qkv_bf;   // reuse q+k+vT+attn (>= NTOK*NMLP)

    unsigned short* qkvW  = wt_bf;
    unsigned short* projW = qkvW  + 768 * 256;
    unsigned short* mlp1W = projW + 256 * 256;
    unsigned short* mlp2W = mlp1W + 1024 * 256;

    wtrans<<<(768 * 256 + 255) / 256, 256, 0, stream>>>(qkv_w, qkvW, CDIM, 3 * CDIM);
    wtrans<<<(256 * 256 + 255) / 256, 256, 0, stream>>>(proj_w, projW, CDIM, CDIM);
    wtrans<<<(1024 * 256 + 255) / 256, 256, 0, stream>>>(mlp_w1, mlp1W, CDIM, NMLP);
    wtrans<<<(256 * 1024 + 255) / 256, 256, 0, stream>>>(mlp_w2, mlp2W, NMLP, CDIM);

    ln_kernel<1><<<NTOK / 4, 256, 0, stream>>>(x, gamma, beta, xw_bf);
    gemm_bt<EPI_QKV><<<dim3(6, NTOK / 128), 256, 0, stream>>>(
        xw_bf, qkvW, CDIM, qkv_b, nullptr, nullptr, qkv_bf);
    attn_mfma<<<BNW * NH / 4, 256, 0, stream>>>(
        qkv_bf, qkv_bf + SZT, qkv_bf + 2 * SZT, rel_t, attn_bf);
    gemm_bt<EPI_PROJ><<<dim3(2, NTOK / 128), 256, 0, stream>>>(
        attn_bf, projW, CDIM, proj_b, x, y1, nullptr);
    ln_kernel<0><<<NTOK / 4, 256, 0, stream>>>(y1, gamma, beta, xw_bf);
    gemm_bt<EPI_MLP1><<<dim3(8, NTOK / 128), 256, 0, stream>>>(
        xw_bf, mlp1W, CDIM, mlp_b1, nullptr, nullptr, h_bf);
    gemm_bt<EPI_MLP2><<<dim3(2, NTOK / 128), 256, 0, stream>>>(
        h_bf, mlp2W, NMLP, mlp_b2, y1, outp, nullptr);
}